// Round 14
// baseline (417.484 us; speedup 1.0000x reference)
//
#include <hip/hip_runtime.h>

#define N_NODES 50000
#define N_EDGES 800000
#define CH 128
#define NBUCK 196          // ceil(50000/256): buckets of 256 dst nodes
#define B_BIN 250          // bin-pass blocks
#define CHUNK 3200         // edges per bin-pass block (250*3200 = 800000)
#define G_GEMM 782         // ceil(50000/64)

typedef __attribute__((ext_vector_type(8))) short bf16x8;
typedef __attribute__((ext_vector_type(8))) unsigned short u16x8;
typedef __attribute__((ext_vector_type(4))) float f32x4;

__device__ __forceinline__ float bf2f(unsigned short u) {
    union { unsigned int i; float f; } c;
    c.i = ((unsigned int)u) << 16;
    return c.f;
}
__device__ __forceinline__ unsigned short f2bf(float f) {
    union { float f; unsigned int i; } c;
    c.f = f;
    unsigned int lsb = (c.i >> 16) & 1u;
    c.i += 0x7fffu + lsb;          // round-to-nearest-even
    return (unsigned short)(c.i >> 16);
}

// ---------------- W transpose to bf16 (parallel): Wt[n][k] = bf16(W[k][n]); 128 blocks ----------------
__global__ __launch_bounds__(256) void k_wt(const float* __restrict__ Wa,
                                            const float* __restrict__ Wb,
                                            unsigned short* __restrict__ Wta,
                                            unsigned short* __restrict__ Wtb) {
    const int b = blockIdx.x;                  // 0..127
    const float* W = (b & 1) ? Wb : Wa;
    unsigned short* Wt = (b & 1) ? Wtb : Wta;
    int idx = (b >> 1) * 256 + threadIdx.x;    // n*128 + k
    int n = idx >> 7, kk = idx & 127;
    Wt[idx] = f2bf(W[kk * CH + n]);
}

// ---------------- mega: blocks [0,B_BIN) = bucket histogram; rest = GEMM1 (unscaled) ----------------
__global__ __launch_bounds__(256) void k_mega(
        const int* __restrict__ ei, int* __restrict__ blk_base,
        const float* __restrict__ X, const unsigned short* __restrict__ Wt1,
        unsigned short* __restrict__ HS1u) {
    const int tid = threadIdx.x;
    const int b = blockIdx.x;

    if (b < B_BIN) {       // ---- bucket histogram ----
        __shared__ int h[NBUCK];
        for (int i = tid; i < NBUCK; i += 256) h[i] = 0;
        __syncthreads();
        const int e0 = b * CHUNK;
        const int* dst = ei + N_EDGES;
        for (int i = tid; i < CHUNK; i += 256)
            atomicAdd(&h[dst[e0 + i] >> 8], 1);
        __syncthreads();
        for (int k = tid; k < NBUCK; k += 256)
            blk_base[b * NBUCK + k] = h[k];
        return;
    }

    // ---- GEMM1 ----
    const int gb = b - B_BIN;
    const int l = tid & 63, w = tid >> 6;
    const int lm = l & 15, lk = l >> 4;
    const int row0 = gb * 64 + w * 16;

    int arow = row0 + lm;
    if (arow >= N_NODES) arow = N_NODES - 1;     // clamp (masked on store)
    bf16x8 a[4];
    #pragma unroll
    for (int ki = 0; ki < 4; ++ki) {
        const float* ap = &X[arow * CH + ki * 32 + lk * 8];
        float4 f0 = *(const float4*)ap;
        float4 f1 = *(const float4*)(ap + 4);
        bf16x8 af;
        af[0] = (short)f2bf(f0.x); af[1] = (short)f2bf(f0.y);
        af[2] = (short)f2bf(f0.z); af[3] = (short)f2bf(f0.w);
        af[4] = (short)f2bf(f1.x); af[5] = (short)f2bf(f1.y);
        af[6] = (short)f2bf(f1.z); af[7] = (short)f2bf(f1.w);
        a[ki] = af;
    }

    #pragma unroll
    for (int ct = 0; ct < 8; ++ct) {
        const unsigned short* wp = &Wt1[(ct * 16 + lm) * CH + lk * 8];
        f32x4 acc = {0.f, 0.f, 0.f, 0.f};
        #pragma unroll
        for (int ki = 0; ki < 4; ++ki) {
            bf16x8 bfrag = *(const bf16x8*)&wp[ki * 32];
            acc = __builtin_amdgcn_mfma_f32_16x16x32_bf16(a[ki], bfrag, acc, 0, 0, 0);
        }
        #pragma unroll
        for (int r = 0; r < 4; ++r) {
            int row = row0 + lk * 4 + r;
            if (row < N_NODES)
                HS1u[row * CH + ct * 16 + lm] = f2bf(acc[r]);
        }
    }
}

// ---------------- column scan + zero the degree-hist bins ----------------
__global__ __launch_bounds__(256) void k_colscan(int* __restrict__ blk_base,
                                                 int* __restrict__ bucket_cnt,
                                                 int* __restrict__ dbin) {
    __shared__ int sm[256];
    const int tid = threadIdx.x, k = blockIdx.x;
    if (k == 0) dbin[tid] = 0;                 // zero 256 degree bins (ordered before bucket_csr)
    int v = (tid < B_BIN) ? blk_base[tid * NBUCK + k] : 0;
    sm[tid] = v;
    __syncthreads();
    #pragma unroll
    for (int off = 1; off < 256; off <<= 1) {
        int t = (tid >= off) ? sm[tid - off] : 0;
        __syncthreads();
        sm[tid] += t;
        __syncthreads();
    }
    if (tid < B_BIN) blk_base[tid * NBUCK + k] = sm[tid] - v;   // exclusive
    if (tid == 255) bucket_cnt[k] = sm[255];
}

// ---------------- place packed edges into bucket-contiguous ebuf (internal bucket scan) ----------------
__global__ __launch_bounds__(256) void k_bin_place(const int* __restrict__ ei,
                                                   const int* __restrict__ bucket_cnt,
                                                   const int* __restrict__ blk_base,
                                                   unsigned int* __restrict__ ebuf) {
    __shared__ int sm[256];
    __shared__ int bbase[NBUCK];
    __shared__ int h[NBUCK];
    const int tid = threadIdx.x, b = blockIdx.x;

    int v = (tid < NBUCK) ? bucket_cnt[tid] : 0;
    sm[tid] = v;
    __syncthreads();
    #pragma unroll
    for (int off = 1; off < 256; off <<= 1) {
        int t = (tid >= off) ? sm[tid - off] : 0;
        __syncthreads();
        sm[tid] += t;
        __syncthreads();
    }
    if (tid < NBUCK) bbase[tid] = sm[tid] - v;   // exclusive bucket base
    for (int i = tid; i < NBUCK; i += 256) h[i] = 0;
    __syncthreads();

    const int e0 = b * CHUNK;
    for (int i = tid; i < CHUNK; i += 256) {
        int s = ei[e0 + i];
        int d = ei[N_EDGES + e0 + i];
        int k = d >> 8;
        int loc = atomicAdd(&h[k], 1);
        int pos = bbase[k] + blk_base[b * NBUCK + k] + loc;
        ebuf[pos] = ((unsigned int)s << 8) | (unsigned int)(d & 255);
    }
}

// ---------------- per-bucket CSR: counts -> rowptr + degc(u8) + degree-hist; place col = src ----------------
__global__ __launch_bounds__(256) void k_bucket_csr(const unsigned int* __restrict__ ebuf,
                                                    const int* __restrict__ bucket_cnt,
                                                    int* __restrict__ rowptr,
                                                    unsigned char* __restrict__ degc,
                                                    int* __restrict__ col,
                                                    int* __restrict__ dbin) {
    __shared__ int cnts[256];
    __shared__ int fillc[256];
    __shared__ int sm[256];
    __shared__ int e0s;
    const int tid = threadIdx.x, k = blockIdx.x;
    const int node0 = k << 8;

    int vb = (tid < NBUCK) ? bucket_cnt[tid] : 0;
    sm[tid] = vb;
    __syncthreads();
    #pragma unroll
    for (int off = 1; off < 256; off <<= 1) {
        int t = (tid >= off) ? sm[tid - off] : 0;
        __syncthreads();
        sm[tid] += t;
        __syncthreads();
    }
    if (tid == k) e0s = sm[tid] - vb;
    cnts[tid] = 0;
    __syncthreads();
    const int e0 = e0s;
    const int cnt = bucket_cnt[k];

    for (int i = tid; i < cnt; i += 256)
        atomicAdd(&cnts[ebuf[e0 + i] & 255], 1);
    __syncthreads();

    int v = cnts[tid];
    sm[tid] = v;
    __syncthreads();
    #pragma unroll
    for (int off = 1; off < 256; off <<= 1) {
        int t = (tid >= off) ? sm[tid - off] : 0;
        __syncthreads();
        sm[tid] += t;
        __syncthreads();
    }
    int rp = sm[tid] - v;              // exclusive prefix within bucket
    fillc[tid] = e0 + rp;              // absolute fill cursor
    int node = node0 + tid;
    if (node < N_NODES) {
        rowptr[node] = e0 + rp;
        int dc = v + 1;                // deg+1 (self loop); max deg ~50 at lambda=16
        if (dc > 255) dc = 255;
        degc[node] = (unsigned char)dc;
        atomicAdd(&dbin[dc], 1);       // degree histogram for the sort
    }
    if (k == NBUCK - 1 && tid == 0) rowptr[N_NODES] = N_EDGES;
    __syncthreads();

    for (int i = tid; i < cnt; i += 256) {
        unsigned int pv = ebuf[e0 + i];
        int loc = atomicAdd(&fillc[pv & 255], 1);
        col[loc] = (int)(pv >> 8);     // plain src index
    }
}

// ---------------- degree-sort: scan bins, then scatter node ids ----------------
__global__ __launch_bounds__(256) void k_degscan(const int* __restrict__ dbin,
                                                 int* __restrict__ dcur) {
    __shared__ int sm[256];
    const int tid = threadIdx.x;
    int v = dbin[tid];
    sm[tid] = v;
    __syncthreads();
    #pragma unroll
    for (int off = 1; off < 256; off <<= 1) {
        int t = (tid >= off) ? sm[tid - off] : 0;
        __syncthreads();
        sm[tid] += t;
        __syncthreads();
    }
    dcur[tid] = sm[tid] - v;           // exclusive
}

__global__ __launch_bounds__(256) void k_degplace(const unsigned char* __restrict__ degc,
                                                  int* __restrict__ dcur,
                                                  int* __restrict__ perm) {
    int node = blockIdx.x * 256 + threadIdx.x;
    if (node < N_NODES) {
        int pos = atomicAdd(&dcur[degc[node]], 1);
        perm[pos] = node;
    }
}

// ---------------- aggregate: 16 lanes/node, u16x8 per lane, unroll-4 gathers, degree-sorted ----------------
// MODE 0 (layer 1, H = unscaled XW1): OUT = bf16( di * relu(di*(di*H[d] + Sum ds*H[s]) + b) )
// MODE 1 (layer 2, H = h1p fully scaled): OUT = bf16( di*(H[d] + Sum H[s]) )
template <int MODE>
__global__ __launch_bounds__(256) void k_agg(
        const int* __restrict__ rowptr, const int* __restrict__ col,
        const unsigned char* __restrict__ degc, const int* __restrict__ perm,
        const unsigned short* __restrict__ H,
        const float* __restrict__ b, unsigned short* __restrict__ OUT) {
    int gid = blockIdx.x * 256 + threadIdx.x;   // 3125 blocks * 256 = 800000 exactly
    int g = gid >> 4;
    if (g >= N_NODES) return;
    int node = perm[g];                          // degree-sorted order
    int lane = gid & 15;
    const u16x8* H8 = (const u16x8*)H;          // 16 u16x8 per 128-ch row

    int e0 = rowptr[node];
    int e1 = rowptr[node + 1];
    float di = rsqrtf((float)(e1 - e0 + 1));    // dinv[node], no memory load

    u16x8 hv = H8[node * 16 + lane];
    float acc[8];
    #pragma unroll
    for (int j = 0; j < 8; ++j)
        acc[j] = MODE == 0 ? bf2f(hv[j]) * di : bf2f(hv[j]);

    int e = e0;
    for (; e + 3 < e1; e += 4) {
        int c0 = col[e], c1 = col[e + 1], c2 = col[e + 2], c3 = col[e + 3];
        u16x8 v0 = H8[c0 * 16 + lane];
        u16x8 v1 = H8[c1 * 16 + lane];
        u16x8 v2 = H8[c2 * 16 + lane];
        u16x8 v3 = H8[c3 * 16 + lane];
        if (MODE == 0) {
            float d0 = rsqrtf((float)degc[c0]);
            float d1 = rsqrtf((float)degc[c1]);
            float d2 = rsqrtf((float)degc[c2]);
            float d3 = rsqrtf((float)degc[c3]);
            #pragma unroll
            for (int j = 0; j < 8; ++j)
                acc[j] += (bf2f(v0[j]) * d0 + bf2f(v1[j]) * d1)
                        + (bf2f(v2[j]) * d2 + bf2f(v3[j]) * d3);
        } else {
            #pragma unroll
            for (int j = 0; j < 8; ++j)
                acc[j] += (bf2f(v0[j]) + bf2f(v1[j])) + (bf2f(v2[j]) + bf2f(v3[j]));
        }
    }
    for (; e < e1; ++e) {
        int c0 = col[e];
        u16x8 v = H8[c0 * 16 + lane];
        if (MODE == 0) {
            float ds = rsqrtf((float)degc[c0]);
            #pragma unroll
            for (int j = 0; j < 8; ++j) acc[j] += bf2f(v[j]) * ds;
        } else {
            #pragma unroll
            for (int j = 0; j < 8; ++j) acc[j] += bf2f(v[j]);
        }
    }

    u16x8 o;
    if (MODE == 0) {
        float4 b0 = *(const float4*)&b[lane * 8];
        float4 b1v = *(const float4*)&b[lane * 8 + 4];
        float bb[8] = {b0.x, b0.y, b0.z, b0.w, b1v.x, b1v.y, b1v.z, b1v.w};
        #pragma unroll
        for (int j = 0; j < 8; ++j)
            o[j] = f2bf(fmaxf(acc[j] * di + bb[j], 0.f) * di);
    } else {
        #pragma unroll
        for (int j = 0; j < 8; ++j)
            o[j] = f2bf(acc[j] * di);
    }
    *(u16x8*)&OUT[node * CH + lane * 8] = o;
}

// ---------------- final GEMM: OUT(f32) = relu(A2 @ W2 + b2) ----------------
__global__ __launch_bounds__(256) void k_gemm_out(
        const unsigned short* __restrict__ A2,   // [N][128] bf16 (= Ahat h1, fully scaled)
        const unsigned short* __restrict__ Wt2,  // [128][128] bf16, n-major
        const float* __restrict__ b2,
        float* __restrict__ OUT) {
    const int tid = threadIdx.x;
    const int l = tid & 63, w = tid >> 6;
    const int lm = l & 15, lk = l >> 4;
    const int row0 = blockIdx.x * 64 + w * 16;

    int arow = row0 + lm;
    if (arow >= N_NODES) arow = N_NODES - 1;     // clamp (masked on store)
    bf16x8 a[4];
    #pragma unroll
    for (int ki = 0; ki < 4; ++ki)
        a[ki] = *(const bf16x8*)&A2[arow * CH + ki * 32 + lk * 8];

    #pragma unroll
    for (int ct = 0; ct < 8; ++ct) {
        const unsigned short* wp = &Wt2[(ct * 16 + lm) * CH + lk * 8];
        f32x4 acc = {0.f, 0.f, 0.f, 0.f};
        #pragma unroll
        for (int ki = 0; ki < 4; ++ki) {
            bf16x8 bfrag = *(const bf16x8*)&wp[ki * 32];
            acc = __builtin_amdgcn_mfma_f32_16x16x32_bf16(a[ki], bfrag, acc, 0, 0, 0);
        }
        float bb = b2[ct * 16 + lm];
        #pragma unroll
        for (int r = 0; r < 4; ++r) {
            int row = row0 + lk * 4 + r;
            if (row < N_NODES)
                OUT[row * CH + ct * 16 + lm] = fmaxf(acc[r] + bb, 0.f);
        }
    }
}

extern "C" void kernel_launch(void* const* d_in, const int* in_sizes, int n_in,
                              void* d_out, int out_size, void* d_ws, size_t ws_size,
                              hipStream_t stream) {
    const float* x  = (const float*)d_in[0];
    const int*   ei = (const int*)d_in[1];
    const float* W1 = (const float*)d_in[2];
    const float* b1 = (const float*)d_in[3];
    const float* W2 = (const float*)d_in[4];
    const float* b2 = (const float*)d_in[5];
    float* out = (float*)d_out;

    // workspace layout (4B units):
    int* blk_base    = (int*)d_ws;               // 250*196 = 49000 -> pad 49152
    int* bucket_cnt  = blk_base + 49152;         // 256
    int* dbin        = bucket_cnt + 256;         // 256
    int* dcur        = dbin + 256;               // 256
    int* rowptr      = dcur + 256;               // 50001 -> pad 50176
    int* perm        = rowptr + 50176;           // 50176
    unsigned char* degc = (unsigned char*)(perm + 50176);     // 50176 bytes -> 12544 words
    int* col         = perm + 50176 + 12544;     // 800000 -> pad 800256
    unsigned int* ebuf = (unsigned int*)(col + 800256);       // 800000 -> pad 800256
    unsigned short* hs1u = (unsigned short*)(ebuf + 800256);  // 6.4M bf16
    unsigned short* h1p = hs1u + 6400000;                     // 6.4M bf16
    unsigned short* a2  = h1p + 6400000;                      // 6.4M bf16
    unsigned short* wt1 = a2 + 6400000;                       // 16384 bf16
    unsigned short* wt2 = wt1 + 16384;                        // 16384 bf16

    const int gAgg = 3125;      // 50000 nodes * 16 lanes / 256

    k_wt<<<128, 256, 0, stream>>>(W1, W2, wt1, wt2);
    k_mega<<<B_BIN + G_GEMM, 256, 0, stream>>>(ei, blk_base, x, wt1, hs1u);
    k_colscan<<<NBUCK, 256, 0, stream>>>(blk_base, bucket_cnt, dbin);
    k_bin_place<<<B_BIN, 256, 0, stream>>>(ei, bucket_cnt, blk_base, ebuf);
    k_bucket_csr<<<NBUCK, 256, 0, stream>>>(ebuf, bucket_cnt, rowptr, degc, col, dbin);
    k_degscan<<<1, 256, 0, stream>>>(dbin, dcur);
    k_degplace<<<NBUCK, 256, 0, stream>>>(degc, dcur, perm);
    k_agg<0><<<gAgg, 256, 0, stream>>>(rowptr, col, degc, perm, hs1u, b1, h1p);
    k_agg<1><<<gAgg, 256, 0, stream>>>(rowptr, col, degc, perm, h1p, nullptr, a2);
    k_gemm_out<<<G_GEMM, 256, 0, stream>>>(a2, wt2, b2, out);
}

// Round 15
// 148.151 us; speedup vs baseline: 2.8180x; 2.8180x over previous
//
#include <hip/hip_runtime.h>

#define N_NODES 50000
#define N_EDGES 800000
#define CH 128
#define NBUCK 196          // ceil(50000/256): buckets of 256 dst nodes
#define B_BIN 250          // bin-pass blocks
#define CHUNK 3200         // edges per bin-pass block (250*3200 = 800000)
#define G_GEMM 782         // ceil(50000/64)

typedef __attribute__((ext_vector_type(8))) short bf16x8;
typedef __attribute__((ext_vector_type(8))) unsigned short u16x8;
typedef __attribute__((ext_vector_type(4))) float f32x4;

__device__ __forceinline__ float bf2f(unsigned short u) {
    union { unsigned int i; float f; } c;
    c.i = ((unsigned int)u) << 16;
    return c.f;
}
__device__ __forceinline__ unsigned short f2bf(float f) {
    union { float f; unsigned int i; } c;
    c.f = f;
    unsigned int lsb = (c.i >> 16) & 1u;
    c.i += 0x7fffu + lsb;          // round-to-nearest-even
    return (unsigned short)(c.i >> 16);
}

// ---------------- W transpose to bf16 (parallel): Wt[n][k] = bf16(W[k][n]); 128 blocks ----------------
__global__ __launch_bounds__(256) void k_wt(const float* __restrict__ Wa,
                                            const float* __restrict__ Wb,
                                            unsigned short* __restrict__ Wta,
                                            unsigned short* __restrict__ Wtb) {
    const int b = blockIdx.x;                  // 0..127
    const float* W = (b & 1) ? Wb : Wa;
    unsigned short* Wt = (b & 1) ? Wtb : Wta;
    int idx = (b >> 1) * 256 + threadIdx.x;    // n*128 + k
    int n = idx >> 7, kk = idx & 127;
    Wt[idx] = f2bf(W[kk * CH + n]);
}

// ---------------- mega: blocks [0,B_BIN) = bucket histogram; rest = GEMM1 (unscaled) ----------------
__global__ __launch_bounds__(256) void k_mega(
        const int* __restrict__ ei, int* __restrict__ blk_base,
        const float* __restrict__ X, const unsigned short* __restrict__ Wt1,
        unsigned short* __restrict__ HS1u) {
    const int tid = threadIdx.x;
    const int b = blockIdx.x;

    if (b < B_BIN) {       // ---- bucket histogram ----
        __shared__ int h[NBUCK];
        for (int i = tid; i < NBUCK; i += 256) h[i] = 0;
        __syncthreads();
        const int e0 = b * CHUNK;
        const int* dst = ei + N_EDGES;
        for (int i = tid; i < CHUNK; i += 256)
            atomicAdd(&h[dst[e0 + i] >> 8], 1);
        __syncthreads();
        for (int k = tid; k < NBUCK; k += 256)
            blk_base[b * NBUCK + k] = h[k];
        return;
    }

    // ---- GEMM1 ----
    const int gb = b - B_BIN;
    const int l = tid & 63, w = tid >> 6;
    const int lm = l & 15, lk = l >> 4;
    const int row0 = gb * 64 + w * 16;

    int arow = row0 + lm;
    if (arow >= N_NODES) arow = N_NODES - 1;     // clamp (masked on store)
    bf16x8 a[4];
    #pragma unroll
    for (int ki = 0; ki < 4; ++ki) {
        const float* ap = &X[arow * CH + ki * 32 + lk * 8];
        float4 f0 = *(const float4*)ap;
        float4 f1 = *(const float4*)(ap + 4);
        bf16x8 af;
        af[0] = (short)f2bf(f0.x); af[1] = (short)f2bf(f0.y);
        af[2] = (short)f2bf(f0.z); af[3] = (short)f2bf(f0.w);
        af[4] = (short)f2bf(f1.x); af[5] = (short)f2bf(f1.y);
        af[6] = (short)f2bf(f1.z); af[7] = (short)f2bf(f1.w);
        a[ki] = af;
    }

    #pragma unroll
    for (int ct = 0; ct < 8; ++ct) {
        const unsigned short* wp = &Wt1[(ct * 16 + lm) * CH + lk * 8];
        f32x4 acc = {0.f, 0.f, 0.f, 0.f};
        #pragma unroll
        for (int ki = 0; ki < 4; ++ki) {
            bf16x8 bfrag = *(const bf16x8*)&wp[ki * 32];
            acc = __builtin_amdgcn_mfma_f32_16x16x32_bf16(a[ki], bfrag, acc, 0, 0, 0);
        }
        #pragma unroll
        for (int r = 0; r < 4; ++r) {
            int row = row0 + lk * 4 + r;
            if (row < N_NODES)
                HS1u[row * CH + ct * 16 + lm] = f2bf(acc[r]);
        }
    }
}

// ---------------- column scan + zero the degree-hist bins ----------------
__global__ __launch_bounds__(256) void k_colscan(int* __restrict__ blk_base,
                                                 int* __restrict__ bucket_cnt,
                                                 int* __restrict__ dbin) {
    __shared__ int sm[256];
    const int tid = threadIdx.x, k = blockIdx.x;
    if (k == 0) dbin[tid] = 0;                 // zero 256 degree bins (ordered before bucket_csr)
    int v = (tid < B_BIN) ? blk_base[tid * NBUCK + k] : 0;
    sm[tid] = v;
    __syncthreads();
    #pragma unroll
    for (int off = 1; off < 256; off <<= 1) {
        int t = (tid >= off) ? sm[tid - off] : 0;
        __syncthreads();
        sm[tid] += t;
        __syncthreads();
    }
    if (tid < B_BIN) blk_base[tid * NBUCK + k] = sm[tid] - v;   // exclusive
    if (tid == 255) bucket_cnt[k] = sm[255];
}

// ---------------- place packed edges into bucket-contiguous ebuf (internal bucket scan) ----------------
__global__ __launch_bounds__(256) void k_bin_place(const int* __restrict__ ei,
                                                   const int* __restrict__ bucket_cnt,
                                                   const int* __restrict__ blk_base,
                                                   unsigned int* __restrict__ ebuf) {
    __shared__ int sm[256];
    __shared__ int bbase[NBUCK];
    __shared__ int h[NBUCK];
    const int tid = threadIdx.x, b = blockIdx.x;

    int v = (tid < NBUCK) ? bucket_cnt[tid] : 0;
    sm[tid] = v;
    __syncthreads();
    #pragma unroll
    for (int off = 1; off < 256; off <<= 1) {
        int t = (tid >= off) ? sm[tid - off] : 0;
        __syncthreads();
        sm[tid] += t;
        __syncthreads();
    }
    if (tid < NBUCK) bbase[tid] = sm[tid] - v;   // exclusive bucket base
    for (int i = tid; i < NBUCK; i += 256) h[i] = 0;
    __syncthreads();

    const int e0 = b * CHUNK;
    for (int i = tid; i < CHUNK; i += 256) {
        int s = ei[e0 + i];
        int d = ei[N_EDGES + e0 + i];
        int k = d >> 8;
        int loc = atomicAdd(&h[k], 1);
        int pos = bbase[k] + blk_base[b * NBUCK + k] + loc;
        ebuf[pos] = ((unsigned int)s << 8) | (unsigned int)(d & 255);
    }
}

// ---------------- per-bucket CSR: counts -> rowptr + degc(u8) + LDS degree-hist; place col = src ----------------
__global__ __launch_bounds__(256) void k_bucket_csr(const unsigned int* __restrict__ ebuf,
                                                    const int* __restrict__ bucket_cnt,
                                                    int* __restrict__ rowptr,
                                                    unsigned char* __restrict__ degc,
                                                    int* __restrict__ col,
                                                    int* __restrict__ dbin) {
    __shared__ int cnts[256];
    __shared__ int fillc[256];
    __shared__ int sm[256];
    __shared__ int dh[256];
    __shared__ int e0s;
    const int tid = threadIdx.x, k = blockIdx.x;
    const int node0 = k << 8;

    int vb = (tid < NBUCK) ? bucket_cnt[tid] : 0;
    sm[tid] = vb;
    __syncthreads();
    #pragma unroll
    for (int off = 1; off < 256; off <<= 1) {
        int t = (tid >= off) ? sm[tid - off] : 0;
        __syncthreads();
        sm[tid] += t;
        __syncthreads();
    }
    if (tid == k) e0s = sm[tid] - vb;
    cnts[tid] = 0;
    dh[tid] = 0;
    __syncthreads();
    const int e0 = e0s;
    const int cnt = bucket_cnt[k];

    for (int i = tid; i < cnt; i += 256)
        atomicAdd(&cnts[ebuf[e0 + i] & 255], 1);
    __syncthreads();

    int v = cnts[tid];
    sm[tid] = v;
    __syncthreads();
    #pragma unroll
    for (int off = 1; off < 256; off <<= 1) {
        int t = (tid >= off) ? sm[tid - off] : 0;
        __syncthreads();
        sm[tid] += t;
        __syncthreads();
    }
    int rp = sm[tid] - v;              // exclusive prefix within bucket
    fillc[tid] = e0 + rp;              // absolute fill cursor
    int node = node0 + tid;
    if (node < N_NODES) {
        rowptr[node] = e0 + rp;
        int dc = v + 1;                // deg+1 (self loop); max deg ~50 at lambda=16
        if (dc > 255) dc = 255;
        degc[node] = (unsigned char)dc;
        atomicAdd(&dh[dc], 1);         // LDS degree histogram (contention-free globally)
    }
    if (k == NBUCK - 1 && tid == 0) rowptr[N_NODES] = N_EDGES;
    __syncthreads();

    if (dh[tid]) atomicAdd(&dbin[tid], dh[tid]);   // ~40 nonzero bins per block

    for (int i = tid; i < cnt; i += 256) {
        unsigned int pv = ebuf[e0 + i];
        int loc = atomicAdd(&fillc[pv & 255], 1);
        col[loc] = (int)(pv >> 8);     // plain src index
    }
}

// ---------------- degree-sort: scan bins, then per-block counting-sort scatter ----------------
__global__ __launch_bounds__(256) void k_degscan(const int* __restrict__ dbin,
                                                 int* __restrict__ dcur) {
    __shared__ int sm[256];
    const int tid = threadIdx.x;
    int v = dbin[tid];
    sm[tid] = v;
    __syncthreads();
    #pragma unroll
    for (int off = 1; off < 256; off <<= 1) {
        int t = (tid >= off) ? sm[tid - off] : 0;
        __syncthreads();
        sm[tid] += t;
        __syncthreads();
    }
    dcur[tid] = sm[tid] - v;           // exclusive
}

__global__ __launch_bounds__(256) void k_degplace(const unsigned char* __restrict__ degc,
                                                  int* __restrict__ dcur,
                                                  int* __restrict__ perm) {
    __shared__ int dh[256];
    __shared__ int dbase[256];
    __shared__ int lcur[256];
    const int tid = threadIdx.x;
    int node = blockIdx.x * 256 + tid;
    bool valid = node < N_NODES;
    int dc = 0;
    dh[tid] = 0;
    __syncthreads();
    if (valid) {
        dc = degc[node];
        atomicAdd(&dh[dc], 1);         // LDS histogram
    }
    __syncthreads();
    if (dh[tid]) dbase[tid] = atomicAdd(&dcur[tid], dh[tid]);  // reserve range (skip-zero)
    lcur[tid] = 0;
    __syncthreads();
    if (valid) {
        int loc = atomicAdd(&lcur[dc], 1);
        perm[dbase[dc] + loc] = node;
    }
}

// ---------------- aggregate: 16 lanes/node, u16x8 per lane, unroll-4 gathers, degree-sorted ----------------
// MODE 0 (layer 1, H = unscaled XW1): OUT = bf16( di * relu(di*(di*H[d] + Sum ds*H[s]) + b) )
// MODE 1 (layer 2, H = h1p fully scaled): OUT = bf16( di*(H[d] + Sum H[s]) )
template <int MODE>
__global__ __launch_bounds__(256) void k_agg(
        const int* __restrict__ rowptr, const int* __restrict__ col,
        const unsigned char* __restrict__ degc, const int* __restrict__ perm,
        const unsigned short* __restrict__ H,
        const float* __restrict__ b, unsigned short* __restrict__ OUT) {
    int gid = blockIdx.x * 256 + threadIdx.x;   // 3125 blocks * 256 = 800000 exactly
    int g = gid >> 4;
    if (g >= N_NODES) return;
    int node = perm[g];                          // degree-sorted order
    int lane = gid & 15;
    const u16x8* H8 = (const u16x8*)H;          // 16 u16x8 per 128-ch row

    int e0 = rowptr[node];
    int e1 = rowptr[node + 1];
    float di = rsqrtf((float)(e1 - e0 + 1));    // dinv[node], no memory load

    u16x8 hv = H8[node * 16 + lane];
    float acc[8];
    #pragma unroll
    for (int j = 0; j < 8; ++j)
        acc[j] = MODE == 0 ? bf2f(hv[j]) * di : bf2f(hv[j]);

    int e = e0;
    for (; e + 3 < e1; e += 4) {
        int c0 = col[e], c1 = col[e + 1], c2 = col[e + 2], c3 = col[e + 3];
        u16x8 v0 = H8[c0 * 16 + lane];
        u16x8 v1 = H8[c1 * 16 + lane];
        u16x8 v2 = H8[c2 * 16 + lane];
        u16x8 v3 = H8[c3 * 16 + lane];
        if (MODE == 0) {
            float d0 = rsqrtf((float)degc[c0]);
            float d1 = rsqrtf((float)degc[c1]);
            float d2 = rsqrtf((float)degc[c2]);
            float d3 = rsqrtf((float)degc[c3]);
            #pragma unroll
            for (int j = 0; j < 8; ++j)
                acc[j] += (bf2f(v0[j]) * d0 + bf2f(v1[j]) * d1)
                        + (bf2f(v2[j]) * d2 + bf2f(v3[j]) * d3);
        } else {
            #pragma unroll
            for (int j = 0; j < 8; ++j)
                acc[j] += (bf2f(v0[j]) + bf2f(v1[j])) + (bf2f(v2[j]) + bf2f(v3[j]));
        }
    }
    for (; e < e1; ++e) {
        int c0 = col[e];
        u16x8 v = H8[c0 * 16 + lane];
        if (MODE == 0) {
            float ds = rsqrtf((float)degc[c0]);
            #pragma unroll
            for (int j = 0; j < 8; ++j) acc[j] += bf2f(v[j]) * ds;
        } else {
            #pragma unroll
            for (int j = 0; j < 8; ++j) acc[j] += bf2f(v[j]);
        }
    }

    u16x8 o;
    if (MODE == 0) {
        float4 b0 = *(const float4*)&b[lane * 8];
        float4 b1v = *(const float4*)&b[lane * 8 + 4];
        float bb[8] = {b0.x, b0.y, b0.z, b0.w, b1v.x, b1v.y, b1v.z, b1v.w};
        #pragma unroll
        for (int j = 0; j < 8; ++j)
            o[j] = f2bf(fmaxf(acc[j] * di + bb[j], 0.f) * di);
    } else {
        #pragma unroll
        for (int j = 0; j < 8; ++j)
            o[j] = f2bf(acc[j] * di);
    }
    *(u16x8*)&OUT[node * CH + lane * 8] = o;
}

// ---------------- final GEMM: OUT(f32) = relu(A2 @ W2 + b2) ----------------
__global__ __launch_bounds__(256) void k_gemm_out(
        const unsigned short* __restrict__ A2,   // [N][128] bf16 (= Ahat h1, fully scaled)
        const unsigned short* __restrict__ Wt2,  // [128][128] bf16, n-major
        const float* __restrict__ b2,
        float* __restrict__ OUT) {
    const int tid = threadIdx.x;
    const int l = tid & 63, w = tid >> 6;
    const int lm = l & 15, lk = l >> 4;
    const int row0 = blockIdx.x * 64 + w * 16;

    int arow = row0 + lm;
    if (arow >= N_NODES) arow = N_NODES - 1;     // clamp (masked on store)
    bf16x8 a[4];
    #pragma unroll
    for (int ki = 0; ki < 4; ++ki)
        a[ki] = *(const bf16x8*)&A2[arow * CH + ki * 32 + lk * 8];

    #pragma unroll
    for (int ct = 0; ct < 8; ++ct) {
        const unsigned short* wp = &Wt2[(ct * 16 + lm) * CH + lk * 8];
        f32x4 acc = {0.f, 0.f, 0.f, 0.f};
        #pragma unroll
        for (int ki = 0; ki < 4; ++ki) {
            bf16x8 bfrag = *(const bf16x8*)&wp[ki * 32];
            acc = __builtin_amdgcn_mfma_f32_16x16x32_bf16(a[ki], bfrag, acc, 0, 0, 0);
        }
        float bb = b2[ct * 16 + lm];
        #pragma unroll
        for (int r = 0; r < 4; ++r) {
            int row = row0 + lk * 4 + r;
            if (row < N_NODES)
                OUT[row * CH + ct * 16 + lm] = fmaxf(acc[r] + bb, 0.f);
        }
    }
}

extern "C" void kernel_launch(void* const* d_in, const int* in_sizes, int n_in,
                              void* d_out, int out_size, void* d_ws, size_t ws_size,
                              hipStream_t stream) {
    const float* x  = (const float*)d_in[0];
    const int*   ei = (const int*)d_in[1];
    const float* W1 = (const float*)d_in[2];
    const float* b1 = (const float*)d_in[3];
    const float* W2 = (const float*)d_in[4];
    const float* b2 = (const float*)d_in[5];
    float* out = (float*)d_out;

    // workspace layout (4B units):
    int* blk_base    = (int*)d_ws;               // 250*196 = 49000 -> pad 49152
    int* bucket_cnt  = blk_base + 49152;         // 256
    int* dbin        = bucket_cnt + 256;         // 256
    int* dcur        = dbin + 256;               // 256
    int* rowptr      = dcur + 256;               // 50001 -> pad 50176
    int* perm        = rowptr + 50176;           // 50176
    unsigned char* degc = (unsigned char*)(perm + 50176);     // 50176 bytes -> 12544 words
    int* col         = perm + 50176 + 12544;     // 800000 -> pad 800256
    unsigned int* ebuf = (unsigned int*)(col + 800256);       // 800000 -> pad 800256
    unsigned short* hs1u = (unsigned short*)(ebuf + 800256);  // 6.4M bf16
    unsigned short* h1p = hs1u + 6400000;                     // 6.4M bf16
    unsigned short* a2  = h1p + 6400000;                      // 6.4M bf16
    unsigned short* wt1 = a2 + 6400000;                       // 16384 bf16
    unsigned short* wt2 = wt1 + 16384;                        // 16384 bf16

    const int gAgg = 3125;      // 50000 nodes * 16 lanes / 256

    k_wt<<<128, 256, 0, stream>>>(W1, W2, wt1, wt2);
    k_mega<<<B_BIN + G_GEMM, 256, 0, stream>>>(ei, blk_base, x, wt1, hs1u);
    k_colscan<<<NBUCK, 256, 0, stream>>>(blk_base, bucket_cnt, dbin);
    k_bin_place<<<B_BIN, 256, 0, stream>>>(ei, bucket_cnt, blk_base, ebuf);
    k_bucket_csr<<<NBUCK, 256, 0, stream>>>(ebuf, bucket_cnt, rowptr, degc, col, dbin);
    k_degscan<<<1, 256, 0, stream>>>(dbin, dcur);
    k_degplace<<<NBUCK, 256, 0, stream>>>(degc, dcur, perm);
    k_agg<0><<<gAgg, 256, 0, stream>>>(rowptr, col, degc, perm, hs1u, b1, h1p);
    k_agg<1><<<gAgg, 256, 0, stream>>>(rowptr, col, degc, perm, h1p, nullptr, a2);
    k_gemm_out<<<G_GEMM, 256, 0, stream>>>(a2, wt2, b2, out);
}

// Round 16
// 138.327 us; speedup vs baseline: 3.0181x; 1.0710x over previous
//
#include <hip/hip_runtime.h>

#define N_NODES 50000
#define N_EDGES 800000
#define CH 128
#define NBUCK 196          // ceil(50000/256): buckets of 256 dst nodes
#define B_BIN 250          // bin-pass blocks
#define CHUNK 3200         // edges per bin-pass block (250*3200 = 800000)
#define G_GEMM 782         // ceil(50000/64)

typedef __attribute__((ext_vector_type(8))) short bf16x8;
typedef __attribute__((ext_vector_type(8))) unsigned short u16x8;
typedef __attribute__((ext_vector_type(4))) float f32x4;

__device__ __forceinline__ float bf2f(unsigned short u) {
    union { unsigned int i; float f; } c;
    c.i = ((unsigned int)u) << 16;
    return c.f;
}
__device__ __forceinline__ unsigned short f2bf(float f) {
    union { float f; unsigned int i; } c;
    c.f = f;
    unsigned int lsb = (c.i >> 16) & 1u;
    c.i += 0x7fffu + lsb;          // round-to-nearest-even
    return (unsigned short)(c.i >> 16);
}

// ---------------- W transpose to bf16 (parallel): Wt[n][k] = bf16(W[k][n]); 128 blocks ----------------
__global__ __launch_bounds__(256) void k_wt(const float* __restrict__ Wa,
                                            const float* __restrict__ Wb,
                                            unsigned short* __restrict__ Wta,
                                            unsigned short* __restrict__ Wtb) {
    const int b = blockIdx.x;                  // 0..127
    const float* W = (b & 1) ? Wb : Wa;
    unsigned short* Wt = (b & 1) ? Wtb : Wta;
    int idx = (b >> 1) * 256 + threadIdx.x;    // n*128 + k
    int n = idx >> 7, kk = idx & 127;
    Wt[idx] = f2bf(W[kk * CH + n]);
}

// ---------------- mega: blocks [0,B_BIN) = bucket histogram; rest = GEMM1 (unscaled) ----------------
__global__ __launch_bounds__(256) void k_mega(
        const int* __restrict__ ei, int* __restrict__ blk_base,
        const float* __restrict__ X, const unsigned short* __restrict__ Wt1,
        unsigned short* __restrict__ HS1u) {
    const int tid = threadIdx.x;
    const int b = blockIdx.x;

    if (b < B_BIN) {       // ---- bucket histogram ----
        __shared__ int h[NBUCK];
        for (int i = tid; i < NBUCK; i += 256) h[i] = 0;
        __syncthreads();
        const int e0 = b * CHUNK;
        const int* dst = ei + N_EDGES;
        for (int i = tid; i < CHUNK; i += 256)
            atomicAdd(&h[dst[e0 + i] >> 8], 1);
        __syncthreads();
        for (int k = tid; k < NBUCK; k += 256)
            blk_base[b * NBUCK + k] = h[k];
        return;
    }

    // ---- GEMM1 ----
    const int gb = b - B_BIN;
    const int l = tid & 63, w = tid >> 6;
    const int lm = l & 15, lk = l >> 4;
    const int row0 = gb * 64 + w * 16;

    int arow = row0 + lm;
    if (arow >= N_NODES) arow = N_NODES - 1;     // clamp (masked on store)
    bf16x8 a[4];
    #pragma unroll
    for (int ki = 0; ki < 4; ++ki) {
        const float* ap = &X[arow * CH + ki * 32 + lk * 8];
        float4 f0 = *(const float4*)ap;
        float4 f1 = *(const float4*)(ap + 4);
        bf16x8 af;
        af[0] = (short)f2bf(f0.x); af[1] = (short)f2bf(f0.y);
        af[2] = (short)f2bf(f0.z); af[3] = (short)f2bf(f0.w);
        af[4] = (short)f2bf(f1.x); af[5] = (short)f2bf(f1.y);
        af[6] = (short)f2bf(f1.z); af[7] = (short)f2bf(f1.w);
        a[ki] = af;
    }

    #pragma unroll
    for (int ct = 0; ct < 8; ++ct) {
        const unsigned short* wp = &Wt1[(ct * 16 + lm) * CH + lk * 8];
        f32x4 acc = {0.f, 0.f, 0.f, 0.f};
        #pragma unroll
        for (int ki = 0; ki < 4; ++ki) {
            bf16x8 bfrag = *(const bf16x8*)&wp[ki * 32];
            acc = __builtin_amdgcn_mfma_f32_16x16x32_bf16(a[ki], bfrag, acc, 0, 0, 0);
        }
        #pragma unroll
        for (int r = 0; r < 4; ++r) {
            int row = row0 + lk * 4 + r;
            if (row < N_NODES)
                HS1u[row * CH + ct * 16 + lm] = f2bf(acc[r]);
        }
    }
}

// ---------------- column scan: per bucket k, exclusive-scan counts over the 250 blocks ----------------
__global__ __launch_bounds__(256) void k_colscan(int* __restrict__ blk_base,
                                                 int* __restrict__ bucket_cnt) {
    __shared__ int sm[256];
    const int tid = threadIdx.x, k = blockIdx.x;
    int v = (tid < B_BIN) ? blk_base[tid * NBUCK + k] : 0;
    sm[tid] = v;
    __syncthreads();
    #pragma unroll
    for (int off = 1; off < 256; off <<= 1) {
        int t = (tid >= off) ? sm[tid - off] : 0;
        __syncthreads();
        sm[tid] += t;
        __syncthreads();
    }
    if (tid < B_BIN) blk_base[tid * NBUCK + k] = sm[tid] - v;   // exclusive
    if (tid == 255) bucket_cnt[k] = sm[255];
}

// ---------------- place packed edges into bucket-contiguous ebuf (internal bucket scan) ----------------
__global__ __launch_bounds__(256) void k_bin_place(const int* __restrict__ ei,
                                                   const int* __restrict__ bucket_cnt,
                                                   const int* __restrict__ blk_base,
                                                   unsigned int* __restrict__ ebuf) {
    __shared__ int sm[256];
    __shared__ int bbase[NBUCK];
    __shared__ int h[NBUCK];
    const int tid = threadIdx.x, b = blockIdx.x;

    int v = (tid < NBUCK) ? bucket_cnt[tid] : 0;
    sm[tid] = v;
    __syncthreads();
    #pragma unroll
    for (int off = 1; off < 256; off <<= 1) {
        int t = (tid >= off) ? sm[tid - off] : 0;
        __syncthreads();
        sm[tid] += t;
        __syncthreads();
    }
    if (tid < NBUCK) bbase[tid] = sm[tid] - v;   // exclusive bucket base
    for (int i = tid; i < NBUCK; i += 256) h[i] = 0;
    __syncthreads();

    const int e0 = b * CHUNK;
    for (int i = tid; i < CHUNK; i += 256) {
        int s = ei[e0 + i];
        int d = ei[N_EDGES + e0 + i];
        int k = d >> 8;
        int loc = atomicAdd(&h[k], 1);
        int pos = bbase[k] + blk_base[b * NBUCK + k] + loc;
        ebuf[pos] = ((unsigned int)s << 8) | (unsigned int)(d & 255);
    }
}

// ---------------- per-bucket CSR: counts -> rowptr + degc(u8); place col = src ----------------
__global__ __launch_bounds__(256) void k_bucket_csr(const unsigned int* __restrict__ ebuf,
                                                    const int* __restrict__ bucket_cnt,
                                                    int* __restrict__ rowptr,
                                                    unsigned char* __restrict__ degc,
                                                    int* __restrict__ col) {
    __shared__ int cnts[256];
    __shared__ int fillc[256];
    __shared__ int sm[256];
    __shared__ int e0s;
    const int tid = threadIdx.x, k = blockIdx.x;
    const int node0 = k << 8;

    int vb = (tid < NBUCK) ? bucket_cnt[tid] : 0;
    sm[tid] = vb;
    __syncthreads();
    #pragma unroll
    for (int off = 1; off < 256; off <<= 1) {
        int t = (tid >= off) ? sm[tid - off] : 0;
        __syncthreads();
        sm[tid] += t;
        __syncthreads();
    }
    if (tid == k) e0s = sm[tid] - vb;
    cnts[tid] = 0;
    __syncthreads();
    const int e0 = e0s;
    const int cnt = bucket_cnt[k];

    for (int i = tid; i < cnt; i += 256)
        atomicAdd(&cnts[ebuf[e0 + i] & 255], 1);
    __syncthreads();

    int v = cnts[tid];
    sm[tid] = v;
    __syncthreads();
    #pragma unroll
    for (int off = 1; off < 256; off <<= 1) {
        int t = (tid >= off) ? sm[tid - off] : 0;
        __syncthreads();
        sm[tid] += t;
        __syncthreads();
    }
    int rp = sm[tid] - v;              // exclusive prefix within bucket
    fillc[tid] = e0 + rp;              // absolute fill cursor
    int node = node0 + tid;
    if (node < N_NODES) {
        rowptr[node] = e0 + rp;
        int dc = v + 1;                // deg+1 (self loop); max deg ~50 at lambda=16
        degc[node] = (unsigned char)(dc > 255 ? 255 : dc);
    }
    if (k == NBUCK - 1 && tid == 0) rowptr[N_NODES] = N_EDGES;
    __syncthreads();

    for (int i = tid; i < cnt; i += 256) {
        unsigned int pv = ebuf[e0 + i];
        int loc = atomicAdd(&fillc[pv & 255], 1);
        col[loc] = (int)(pv >> 8);     // plain src index
    }
}

// ---------------- aggregate: 16 lanes/node, u16x8 per lane, unroll-4 gathers ----------------
// MODE 0 (layer 1, H = unscaled XW1): OUT = bf16( di * relu(di*(di*H[d] + Sum ds*H[s]) + b) )
//   ds = rsqrt(degc[s]) — 1-byte L2-resident load per edge, overlaps the row gather.
// MODE 1 (layer 2, H = h1p fully scaled): OUT = bf16( di*(H[d] + Sum H[s]) )
template <int MODE>
__global__ __launch_bounds__(256) void k_agg(
        const int* __restrict__ rowptr, const int* __restrict__ col,
        const unsigned char* __restrict__ degc,
        const unsigned short* __restrict__ H,
        const float* __restrict__ b, unsigned short* __restrict__ OUT) {
    int gid = blockIdx.x * 256 + threadIdx.x;   // 3125 blocks * 256 = 800000 exactly
    int node = gid >> 4;
    if (node >= N_NODES) return;
    int lane = gid & 15;
    const u16x8* H8 = (const u16x8*)H;          // 16 u16x8 per 128-ch row

    int e0 = rowptr[node];
    int e1 = rowptr[node + 1];
    float di = rsqrtf((float)(e1 - e0 + 1));    // dinv[node], no memory load

    u16x8 hv = H8[node * 16 + lane];
    float acc[8];
    #pragma unroll
    for (int j = 0; j < 8; ++j)
        acc[j] = MODE == 0 ? bf2f(hv[j]) * di : bf2f(hv[j]);

    int e = e0;
    for (; e + 3 < e1; e += 4) {
        int c0 = col[e], c1 = col[e + 1], c2 = col[e + 2], c3 = col[e + 3];
        u16x8 v0 = H8[c0 * 16 + lane];
        u16x8 v1 = H8[c1 * 16 + lane];
        u16x8 v2 = H8[c2 * 16 + lane];
        u16x8 v3 = H8[c3 * 16 + lane];
        if (MODE == 0) {
            float d0 = rsqrtf((float)degc[c0]);
            float d1 = rsqrtf((float)degc[c1]);
            float d2 = rsqrtf((float)degc[c2]);
            float d3 = rsqrtf((float)degc[c3]);
            #pragma unroll
            for (int j = 0; j < 8; ++j)
                acc[j] += (bf2f(v0[j]) * d0 + bf2f(v1[j]) * d1)
                        + (bf2f(v2[j]) * d2 + bf2f(v3[j]) * d3);
        } else {
            #pragma unroll
            for (int j = 0; j < 8; ++j)
                acc[j] += (bf2f(v0[j]) + bf2f(v1[j])) + (bf2f(v2[j]) + bf2f(v3[j]));
        }
    }
    for (; e < e1; ++e) {
        int c0 = col[e];
        u16x8 v = H8[c0 * 16 + lane];
        if (MODE == 0) {
            float ds = rsqrtf((float)degc[c0]);
            #pragma unroll
            for (int j = 0; j < 8; ++j) acc[j] += bf2f(v[j]) * ds;
        } else {
            #pragma unroll
            for (int j = 0; j < 8; ++j) acc[j] += bf2f(v[j]);
        }
    }

    u16x8 o;
    if (MODE == 0) {
        float4 b0 = *(const float4*)&b[lane * 8];
        float4 b1v = *(const float4*)&b[lane * 8 + 4];
        float bb[8] = {b0.x, b0.y, b0.z, b0.w, b1v.x, b1v.y, b1v.z, b1v.w};
        #pragma unroll
        for (int j = 0; j < 8; ++j)
            o[j] = f2bf(fmaxf(acc[j] * di + bb[j], 0.f) * di);
    } else {
        #pragma unroll
        for (int j = 0; j < 8; ++j)
            o[j] = f2bf(acc[j] * di);
    }
    *(u16x8*)&OUT[node * CH + lane * 8] = o;
}

// ---------------- final GEMM: OUT(f32) = relu(A2 @ W2 + b2) ----------------
__global__ __launch_bounds__(256) void k_gemm_out(
        const unsigned short* __restrict__ A2,   // [N][128] bf16 (= Ahat h1, fully scaled)
        const unsigned short* __restrict__ Wt2,  // [128][128] bf16, n-major
        const float* __restrict__ b2,
        float* __restrict__ OUT) {
    const int tid = threadIdx.x;
    const int l = tid & 63, w = tid >> 6;
    const int lm = l & 15, lk = l >> 4;
    const int row0 = blockIdx.x * 64 + w * 16;

    int arow = row0 + lm;
    if (arow >= N_NODES) arow = N_NODES - 1;     // clamp (masked on store)
    bf16x8 a[4];
    #pragma unroll
    for (int ki = 0; ki < 4; ++ki)
        a[ki] = *(const bf16x8*)&A2[arow * CH + ki * 32 + lk * 8];

    #pragma unroll
    for (int ct = 0; ct < 8; ++ct) {
        const unsigned short* wp = &Wt2[(ct * 16 + lm) * CH + lk * 8];
        f32x4 acc = {0.f, 0.f, 0.f, 0.f};
        #pragma unroll
        for (int ki = 0; ki < 4; ++ki) {
            bf16x8 bfrag = *(const bf16x8*)&wp[ki * 32];
            acc = __builtin_amdgcn_mfma_f32_16x16x32_bf16(a[ki], bfrag, acc, 0, 0, 0);
        }
        float bb = b2[ct * 16 + lm];
        #pragma unroll
        for (int r = 0; r < 4; ++r) {
            int row = row0 + lk * 4 + r;
            if (row < N_NODES)
                OUT[row * CH + ct * 16 + lm] = fmaxf(acc[r] + bb, 0.f);
        }
    }
}

extern "C" void kernel_launch(void* const* d_in, const int* in_sizes, int n_in,
                              void* d_out, int out_size, void* d_ws, size_t ws_size,
                              hipStream_t stream) {
    const float* x  = (const float*)d_in[0];
    const int*   ei = (const int*)d_in[1];
    const float* W1 = (const float*)d_in[2];
    const float* b1 = (const float*)d_in[3];
    const float* W2 = (const float*)d_in[4];
    const float* b2 = (const float*)d_in[5];
    float* out = (float*)d_out;

    // workspace layout (4B units):
    int* blk_base    = (int*)d_ws;               // 250*196 = 49000 -> pad 49152
    int* bucket_cnt  = blk_base + 49152;         // 256
    int* rowptr      = bucket_cnt + 256;         // 50001 -> pad 50176
    unsigned char* degc = (unsigned char*)(rowptr + 50176);   // 50176 bytes -> 12544 words
    int* col         = rowptr + 50176 + 12544;   // 800000 -> pad 800256
    unsigned int* ebuf = (unsigned int*)(col + 800256);       // 800000 -> pad 800256
    unsigned short* hs1u = (unsigned short*)(ebuf + 800256);  // 6.4M bf16
    unsigned short* h1p = hs1u + 6400000;                     // 6.4M bf16
    unsigned short* a2  = h1p + 6400000;                      // 6.4M bf16
    unsigned short* wt1 = a2 + 6400000;                       // 16384 bf16
    unsigned short* wt2 = wt1 + 16384;                        // 16384 bf16

    const int gAgg = 3125;      // 50000 nodes * 16 lanes / 256

    k_wt<<<128, 256, 0, stream>>>(W1, W2, wt1, wt2);
    k_mega<<<B_BIN + G_GEMM, 256, 0, stream>>>(ei, blk_base, x, wt1, hs1u);
    k_colscan<<<NBUCK, 256, 0, stream>>>(blk_base, bucket_cnt);
    k_bin_place<<<B_BIN, 256, 0, stream>>>(ei, bucket_cnt, blk_base, ebuf);
    k_bucket_csr<<<NBUCK, 256, 0, stream>>>(ebuf, bucket_cnt, rowptr, degc, col);
    k_agg<0><<<gAgg, 256, 0, stream>>>(rowptr, col, degc, hs1u, b1, h1p);    // h1p = dinv*relu(...)
    k_agg<1><<<gAgg, 256, 0, stream>>>(rowptr, col, degc, h1p, nullptr, a2); // a2 = Ahat h1
    k_gemm_out<<<G_GEMM, 256, 0, stream>>>(a2, wt2, b2, out);
}